// Round 1
// baseline (135.732 us; speedup 1.0000x reference)
//
#include <hip/hip_runtime.h>

#define LSEQ 4096
#define ROWS_PER_BLOCK 4
#define NBLOCKS (LSEQ / ROWS_PER_BLOCK)   // 1024
#define NTHREADS 256

#define IDEAL 6.0f
#define MIN_DIST 3.4f
#define TARGET 9.0f   // 1.5 * IDEAL
#define W_BOND 1.0f
#define W_CLASH 2.0f
#define W_PAIR 0.5f

// d_ws layout: ws[0] = clash_sum (float), ws[1] = pair_sum (float), ws[2] = n_pairs (uint bits)
__global__ void er_init_ws(float* ws) {
    if (threadIdx.x < 4) ws[threadIdx.x] = 0.0f;   // 0 bits == 0.0f == 0u
}

__global__ __launch_bounds__(NTHREADS) void er_pair_kernel(
        const float* __restrict__ coords,
        const float* __restrict__ cmap,
        float* __restrict__ ws) {
    const int t = threadIdx.x;
    const int row0 = blockIdx.x * ROWS_PER_BLOCK;

    // Preload this thread's 16 j-columns' coords into registers.
    // j = 4*t + 1024*k + q, k in [0,4), q in [0,4).
    // float offset 3*j -> 12t + 3072k, byte offset 48t + 12288k: 16B aligned.
    float xj[16], yj[16], zj[16];
    const float4* cp4 = (const float4*)coords;
#pragma unroll
    for (int k = 0; k < 4; ++k) {
        float4 a = cp4[3 * t + 768 * k + 0];
        float4 b = cp4[3 * t + 768 * k + 1];
        float4 c = cp4[3 * t + 768 * k + 2];
        // 12 floats = coords of 4 consecutive j
        xj[k * 4 + 0] = a.x; yj[k * 4 + 0] = a.y; zj[k * 4 + 0] = a.z;
        xj[k * 4 + 1] = a.w; yj[k * 4 + 1] = b.x; zj[k * 4 + 1] = b.y;
        xj[k * 4 + 2] = b.z; yj[k * 4 + 2] = b.w; zj[k * 4 + 2] = c.x;
        xj[k * 4 + 3] = c.y; yj[k * 4 + 3] = c.z; zj[k * 4 + 3] = c.w;
    }

    float clash_acc = 0.0f;
    float pair_acc = 0.0f;
    unsigned int cnt = 0;

    for (int r = 0; r < ROWS_PER_BLOCK; ++r) {
        const int i = row0 + r;
        // wave-uniform -> compiler emits scalar loads
        const float xi = coords[3 * i + 0];
        const float yi = coords[3 * i + 1];
        const float zi = coords[3 * i + 2];
        const float4* crow = (const float4*)(cmap + (size_t)i * LSEQ);
#pragma unroll
        for (int k = 0; k < 4; ++k) {
            const int jbase = 4 * t + 1024 * k;
            const float4 c4 = crow[t + 256 * k];   // coalesced 16B/lane
            const float cv[4] = {c4.x, c4.y, c4.z, c4.w};
#pragma unroll
            for (int q = 0; q < 4; ++q) {
                const int j = jbase + q;
                const int idx = k * 4 + q;
                const float dx = xi - xj[idx];
                const float dy = yi - yj[idx];
                const float dz = zi - zj[idx];
                const float d2 = dx * dx + dy * dy + dz * dz;
                const float d = sqrtf(d2) + 1e-8f;
                const int sep = j - i;
                // clash: upper triangle only (sep >= 3)
                float cl = fmaxf(MIN_DIST - d, 0.0f);
                cl = (sep >= 3) ? cl : 0.0f;
                clash_acc += cl * cl;
                // pair: contact & |sep| >= 3 ; n_pairs counts ALL contacts
                const bool contact = cv[q] > 0.5f;
                cnt += contact ? 1u : 0u;
                float pd = d - TARGET;
                pd = (contact && (sep >= 3 || sep <= -3)) ? pd : 0.0f;
                pair_acc += pd * pd;
            }
        }
    }

    // wave (64-lane) reduction
#pragma unroll
    for (int off = 32; off > 0; off >>= 1) {
        clash_acc += __shfl_down(clash_acc, off);
        pair_acc  += __shfl_down(pair_acc, off);
        cnt       += __shfl_down(cnt, off);
    }
    __shared__ float s_clash[NTHREADS / 64];
    __shared__ float s_pair[NTHREADS / 64];
    __shared__ unsigned int s_cnt[NTHREADS / 64];
    const int wave = t >> 6;
    const int lane = t & 63;
    if (lane == 0) { s_clash[wave] = clash_acc; s_pair[wave] = pair_acc; s_cnt[wave] = cnt; }
    __syncthreads();
    if (t == 0) {
        float cs = 0.0f, ps = 0.0f;
        unsigned int ns = 0;
#pragma unroll
        for (int w = 0; w < NTHREADS / 64; ++w) { cs += s_clash[w]; ps += s_pair[w]; ns += s_cnt[w]; }
        atomicAdd(&ws[0], cs);
        atomicAdd(&ws[1], ps);
        atomicAdd((unsigned int*)&ws[2], ns);
    }
}

__global__ __launch_bounds__(NTHREADS) void er_finalize(
        const float* __restrict__ coords,
        const float* __restrict__ ws,
        float* __restrict__ out) {
    const int t = threadIdx.x;
    float bacc = 0.0f;
    for (int b = t; b < LSEQ - 1; b += NTHREADS) {
        const float dx = coords[3 * (b + 1) + 0] - coords[3 * b + 0];
        const float dy = coords[3 * (b + 1) + 1] - coords[3 * b + 1];
        const float dz = coords[3 * (b + 1) + 2] - coords[3 * b + 2];
        const float d = sqrtf(dx * dx + dy * dy + dz * dz);  // no +1e-8 in bond term
        const float e = d - IDEAL;
        bacc += e * e;
    }
#pragma unroll
    for (int off = 32; off > 0; off >>= 1) bacc += __shfl_down(bacc, off);
    __shared__ float sb[NTHREADS / 64];
    const int wave = t >> 6;
    const int lane = t & 63;
    if (lane == 0) sb[wave] = bacc;
    __syncthreads();
    if (t == 0) {
        float bs = 0.0f;
#pragma unroll
        for (int w = 0; w < NTHREADS / 64; ++w) bs += sb[w];
        const float e_bond = bs / (float)(LSEQ - 1);
        const float e_clash = ws[0] / (float)LSEQ;
        const unsigned int n = ((const unsigned int*)ws)[2];
        const float e_pair = ws[1] / (float)(n > 0u ? n : 1u);
        out[0] = W_BOND * e_bond + W_CLASH * e_clash + W_PAIR * e_pair;
    }
}

extern "C" void kernel_launch(void* const* d_in, const int* in_sizes, int n_in,
                              void* d_out, int out_size, void* d_ws, size_t ws_size,
                              hipStream_t stream) {
    const float* coords = (const float*)d_in[0];
    const float* cmap   = (const float*)d_in[1];
    float* ws  = (float*)d_ws;
    float* out = (float*)d_out;

    hipLaunchKernelGGL(er_init_ws, dim3(1), dim3(64), 0, stream, ws);
    hipLaunchKernelGGL(er_pair_kernel, dim3(NBLOCKS), dim3(NTHREADS), 0, stream,
                       coords, cmap, ws);
    hipLaunchKernelGGL(er_finalize, dim3(1), dim3(NTHREADS), 0, stream,
                       coords, ws, out);
}

// Round 2
// 107.572 us; speedup vs baseline: 1.2618x; 1.2618x over previous
//
#include <hip/hip_runtime.h>

#define LSEQ 4096
#define ROWS 2
#define NB (LSEQ / ROWS)   // 2048 blocks -> 8 blocks/CU on 256 CUs = 32 waves/CU
#define NT 256

#define IDEAL 6.0f
#define MIN_DIST 3.4f
#define TARGET 9.0f   // 1.5 * IDEAL
#define W_BOND 1.0f
#define W_CLASH 2.0f
#define W_PAIR 0.5f

// slot mode ws layout: ws[0..NB) clash partials, ws[NB..2NB) pair partials,
//                      ws[2NB..3NB) contact counts (uint bits)
// atomic fallback:     ws[0]=clash, ws[1]=pair, ws[2]=cnt (needs init kernel)

__global__ void er_init_ws(float* ws) {
    if (threadIdx.x < 4) ws[threadIdx.x] = 0.0f;
}

__global__ __launch_bounds__(NT, 6) void er_pair_kernel(
        const float* __restrict__ coords,
        const float* __restrict__ cmap,
        float* __restrict__ ws,
        int slot_mode) {
    const int t = threadIdx.x;
    const int b = blockIdx.x;
    const int row0 = b * ROWS;

    // Preload this thread's 16 j-columns' coords into registers.
    // j = 4*t + 1024*k + q ; float4 index = 3t + 768k (16B aligned).
    float xj[16], yj[16], zj[16];
    const float4* cp4 = (const float4*)coords;
#pragma unroll
    for (int k = 0; k < 4; ++k) {
        float4 a = cp4[3 * t + 768 * k + 0];
        float4 bb = cp4[3 * t + 768 * k + 1];
        float4 c = cp4[3 * t + 768 * k + 2];
        xj[k * 4 + 0] = a.x;  yj[k * 4 + 0] = a.y;  zj[k * 4 + 0] = a.z;
        xj[k * 4 + 1] = a.w;  yj[k * 4 + 1] = bb.x; zj[k * 4 + 1] = bb.y;
        xj[k * 4 + 2] = bb.z; yj[k * 4 + 2] = bb.w; zj[k * 4 + 2] = c.x;
        xj[k * 4 + 3] = c.y;  yj[k * 4 + 3] = c.z;  zj[k * 4 + 3] = c.w;
    }

    float clash_acc = 0.0f;
    float pair_acc = 0.0f;
    unsigned int cnt = 0;   // wave-uniform (ballot/popcount)

#pragma unroll
    for (int r = 0; r < ROWS; ++r) {
        const int i = row0 + r;
        const float xi = coords[3 * i + 0];   // wave-uniform -> scalar loads
        const float yi = coords[3 * i + 1];
        const float zi = coords[3 * i + 2];
        const float4* crow = (const float4*)(cmap + (size_t)i * LSEQ);
        // hoist all 4 contact-row loads: 4 x 16B/lane in flight
        float4 c4[4];
#pragma unroll
        for (int k = 0; k < 4; ++k) c4[k] = crow[t + 256 * k];
#pragma unroll
        for (int k = 0; k < 4; ++k) {
            const float cv[4] = {c4[k].x, c4[k].y, c4[k].z, c4[k].w};
            const int jbase = 4 * t + 1024 * k;
#pragma unroll
            for (int q = 0; q < 4; ++q) {
                const int j = jbase + q;
                const int idx = k * 4 + q;
                const float dx = xi - xj[idx];
                const float dy = yi - yj[idx];
                const float dz = zi - zj[idx];
                const float d2 = dx * dx + dy * dy + dz * dz;
                const float d = sqrtf(d2) + 1e-8f;
                const int sep = j - i;
                // clash: upper triangle, sep >= 3
                float cl = fmaxf(MIN_DIST - d, 0.0f);
                cl = (sep >= 3) ? cl : 0.0f;
                clash_acc = fmaf(cl, cl, clash_acc);
                // contact count: ballot -> scalar popcount (wave-uniform)
                const bool contact = cv[q] > 0.5f;
                cnt += (unsigned int)__popcll(__ballot(contact));
                // pair: contact && |sep| >= 3  (|sep|<3 <=> (unsigned)(sep+2)<=4)
                const bool pg = contact && ((unsigned int)(sep + 2) > 4u);
                float pd = pg ? (d - TARGET) : 0.0f;
                pair_acc = fmaf(pd, pd, pair_acc);
            }
        }
    }

    // 64-lane reduction (cnt already wave-uniform)
#pragma unroll
    for (int off = 32; off > 0; off >>= 1) {
        clash_acc += __shfl_down(clash_acc, off);
        pair_acc  += __shfl_down(pair_acc, off);
    }
    __shared__ float s_clash[NT / 64];
    __shared__ float s_pair[NT / 64];
    __shared__ unsigned int s_cnt[NT / 64];
    const int wave = t >> 6;
    const int lane = t & 63;
    if (lane == 0) { s_clash[wave] = clash_acc; s_pair[wave] = pair_acc; s_cnt[wave] = cnt; }
    __syncthreads();
    if (t == 0) {
        float cs = 0.0f, ps = 0.0f;
        unsigned int ns = 0;
#pragma unroll
        for (int w = 0; w < NT / 64; ++w) { cs += s_clash[w]; ps += s_pair[w]; ns += s_cnt[w]; }
        if (slot_mode) {
            ws[b] = cs;
            ws[NB + b] = ps;
            ((unsigned int*)ws)[2 * NB + b] = ns;
        } else {
            atomicAdd(&ws[0], cs);
            atomicAdd(&ws[1], ps);
            atomicAdd((unsigned int*)&ws[2], ns);
        }
    }
}

__global__ __launch_bounds__(NT) void er_finalize(
        const float* __restrict__ coords,
        const float* __restrict__ ws,
        float* __restrict__ out,
        int slot_mode) {
    const int t = threadIdx.x;
    float cs = 0.0f, ps = 0.0f;
    unsigned int ns = 0;
    if (slot_mode) {
        for (int idx = t; idx < NB; idx += NT) {
            cs += ws[idx];
            ps += ws[NB + idx];
            ns += ((const unsigned int*)ws)[2 * NB + idx];
        }
    } else if (t == 0) {
        cs = ws[0];
        ps = ws[1];
        ns = ((const unsigned int*)ws)[2];
    }
    // bond term
    float bacc = 0.0f;
    for (int b = t; b < LSEQ - 1; b += NT) {
        const float dx = coords[3 * (b + 1) + 0] - coords[3 * b + 0];
        const float dy = coords[3 * (b + 1) + 1] - coords[3 * b + 1];
        const float dz = coords[3 * (b + 1) + 2] - coords[3 * b + 2];
        const float d = sqrtf(dx * dx + dy * dy + dz * dz);
        const float e = d - IDEAL;
        bacc += e * e;
    }
#pragma unroll
    for (int off = 32; off > 0; off >>= 1) {
        cs += __shfl_down(cs, off);
        ps += __shfl_down(ps, off);
        ns += __shfl_down(ns, off);
        bacc += __shfl_down(bacc, off);
    }
    __shared__ float sc[NT / 64], sp[NT / 64], sb[NT / 64];
    __shared__ unsigned int sn[NT / 64];
    const int wave = t >> 6;
    const int lane = t & 63;
    if (lane == 0) { sc[wave] = cs; sp[wave] = ps; sn[wave] = ns; sb[wave] = bacc; }
    __syncthreads();
    if (t == 0) {
        float tc = 0.0f, tp = 0.0f, tb = 0.0f;
        unsigned int tn = 0;
#pragma unroll
        for (int w = 0; w < NT / 64; ++w) { tc += sc[w]; tp += sp[w]; tn += sn[w]; tb += sb[w]; }
        const float e_bond = tb / (float)(LSEQ - 1);
        const float e_clash = tc / (float)LSEQ;
        const float e_pair = tp / (float)(tn > 0u ? tn : 1u);
        out[0] = W_BOND * e_bond + W_CLASH * e_clash + W_PAIR * e_pair;
    }
}

extern "C" void kernel_launch(void* const* d_in, const int* in_sizes, int n_in,
                              void* d_out, int out_size, void* d_ws, size_t ws_size,
                              hipStream_t stream) {
    const float* coords = (const float*)d_in[0];
    const float* cmap   = (const float*)d_in[1];
    float* ws  = (float*)d_ws;
    float* out = (float*)d_out;

    const int slot_mode = (ws_size >= (size_t)(3 * NB * 4)) ? 1 : 0;
    if (!slot_mode) {
        hipLaunchKernelGGL(er_init_ws, dim3(1), dim3(64), 0, stream, ws);
    }
    hipLaunchKernelGGL(er_pair_kernel, dim3(NB), dim3(NT), 0, stream,
                       coords, cmap, ws, slot_mode);
    hipLaunchKernelGGL(er_finalize, dim3(1), dim3(NT), 0, stream,
                       coords, ws, out, slot_mode);
}